// Round 9
// baseline (1108.957 us; speedup 1.0000x reference)
//
#include <hip/hip_runtime.h>

// ---------------- problem constants ----------------
#define Bb 10
#define Hh 50
#define Ww 101
#define Kk 4096

// conv1: IC=3 OC=32 k7 s2 p3 -> [32,25,51]; pool1 k3 s2 -> [32,12,25]
// conv2: IC=32 OC=64 k5 s1 p2 -> [64,12,25]; pool2 k2 s2 -> [64,6,12]
// conv3: IC=64 OC=128 k3 s1 p1 -> [128,6,12]; pool3 k2 s2 -> [128,3,6]
// head: mean(18) -> fc128 relu -> fc5

// ONE kernel, 10 blocks (one per batch) x 1024 threads. All stage-to-stage
// dataflow is within-block (LDS or same-block global roundtrips), so only
// __syncthreads() is needed -- no cross-block coherence, no atomic counters,
// one graph node.
//
// LDS budget (union, peak 64864 B < 65536):
//   phase S/C1: lastKp[52*104] int @0 (21632) | padF[56*109] @21632 (24416)
//               | w1s[4704] @46048 (18816)  -> 64864
//   phase C2  : lds2[32*16*29] @0 (59392)
//   phase C3  : lds3[64*8*14] @0 (28672) | red[2304] @28672 (9216)
//               | feat[128] @37888 | h2[128] @38400
__global__ __launch_bounds__(1024) void mega_b_kernel(
        const int* __restrict__ x,
        const float* __restrict__ w1, const float* __restrict__ b1,
        const float* __restrict__ w2, const float* __restrict__ b2,
        const float* __restrict__ w3, const float* __restrict__ b3,
        const float* __restrict__ wl1, const float* __restrict__ bl1,
        const float* __restrict__ wl2, const float* __restrict__ bl2,
        float* __restrict__ conv1out,   // [10][32][25][51] scratch
        float* __restrict__ p2g,        // [10][64][6][12] scratch
        float* __restrict__ out) {
    __shared__ __align__(16) char smem[64864];
    int*   lastKp = (int*)smem;                    // 52*104
    float* padF   = (float*)(smem + 21632);        // 56*109
    float* w1s    = (float*)(smem + 46048);        // 32*3*49
    float* lds2   = (float*)smem;                  // 32*16*29
    float* lds3   = (float*)smem;                  // 64*8*14
    float* red    = (float*)(smem + 28672);        // 128*18
    float* feat   = (float*)(smem + 37888);        // 128
    float* h2     = (float*)(smem + 38400);        // 128

    int b = blockIdx.x;
    int tid = threadIdx.x;

    // stage w1 into LDS once (coalesced); consumed after >=2 syncs below
    for (int i = tid; i < 32 * 3 * 49; i += 1024) w1s[i] = w1[i];

    // ---- per-thread conv1 task precompute: 5200 tasks = 16 ocpair x 25 oh x 13 owt
    int   oc0_[6], rowoff_[6];
    bool  valid_[6];
    float a0[6][4], a1[6][4];
    #pragma unroll
    for (int j = 0; j < 6; ++j) {
        int t = tid + j * 1024;
        valid_[j] = t < 5200;
        int tt = valid_[j] ? t : 0;
        int ocp = tt / 325, rem = tt % 325;
        int oh = rem / 13, owt = rem % 13;
        oc0_[j] = ocp * 2;
        rowoff_[j] = (2 * oh) * 109 + 2 * (owt * 4);
        #pragma unroll
        for (int jj = 0; jj < 4; ++jj) { a0[j][jj] = 0.f; a1[j][jj] = 0.f; }
    }

    // =================== scatter + dilate + conv1 (per ic) ===================
    for (int ic = 0; ic < 3; ++ic) {
        for (int i = tid; i < 52 * 104; i += 1024) lastKp[i] = -1;
        __syncthreads();
        const int2* xp = (const int2*)(x + (b * 3 + ic) * Kk * 2);   // (col,row)
        for (int k = tid; k < Kk + 1; k += 1024) {
            int col, row;
            if (k == 0) { col = 50; row = 48; }        // prepended base fill
            else { int2 p = xp[k - 1]; col = p.x; row = p.y; }
            atomicMax(&lastKp[(row + 1) * 104 + (col + 1)], k);
        }
        __syncthreads();
        // decode + 3x3 max-dilate into zero-padded float tile [56][109] (pad=3)
        for (int i = tid; i < 56 * 109; i += 1024) {
            int r = i / 109, c = i % 109;
            int gr = r - 3, gc = c - 3;
            float v = 0.f;
            if (gr >= 0 && gr < Hh && gc >= 0 && gc < Ww) {
                const int* ctr = &lastKp[(gr + 1) * 104 + (gc + 1)];
                int M = ctr[0];
                M = max(M, ctr[-1]);   M = max(M, ctr[1]);
                M = max(M, ctr[-104]); M = max(M, ctr[-105]); M = max(M, ctr[-103]);
                M = max(M, ctr[104]);  M = max(M, ctr[103]);  M = max(M, ctr[105]);
                v = (M < 0) ? 0.0f : ((ctr[0] == M) ? 1.0f : 0.5f);
            }
            padF[i] = v;
        }
        __syncthreads();
        // conv1 accumulate (persistent acc across ic)
        #pragma unroll
        for (int j = 0; j < 6; ++j) {
            if (!valid_[j]) continue;
            const float* wp0 = w1s + (oc0_[j] * 3 + ic) * 49;
            const float* wp1 = w1s + ((oc0_[j] + 1) * 3 + ic) * 49;
            #pragma unroll
            for (int kh = 0; kh < 7; ++kh) {
                const float* lr = padF + rowoff_[j] + kh * 109;
                float s[13];
                #pragma unroll
                for (int k = 0; k < 13; ++k) s[k] = lr[k];
                float wa[7], wb_[7];
                #pragma unroll
                for (int k = 0; k < 7; ++k) { wa[k] = wp0[kh * 7 + k]; wb_[k] = wp1[kh * 7 + k]; }
                #pragma unroll
                for (int kw = 0; kw < 7; ++kw)
                    #pragma unroll
                    for (int jj = 0; jj < 4; ++jj) {
                        a0[j][jj] += s[2 * jj + kw] * wa[kw];
                        a1[j][jj] += s[2 * jj + kw] * wb_[kw];
                    }
            }
        }
        __syncthreads();   // padF/lastKp rewritten next ic
    }
    // write conv1 (bias+relu) to global scratch (L2-hot, same block reads back)
    float* c1b = conv1out + b * 32 * 25 * 51;
    #pragma unroll
    for (int j = 0; j < 6; ++j) {
        if (!valid_[j]) continue;
        int t = tid + j * 1024;
        int ocp = t / 325, rem = t % 325;
        int oh = rem / 13, ow0 = (rem % 13) * 4;
        int oc0 = ocp * 2;
        float bia0 = b1[oc0], bia1 = b1[oc0 + 1];
        #pragma unroll
        for (int jj = 0; jj < 4; ++jj) {
            int ow = ow0 + jj;
            if (ow < 51) {
                c1b[(oc0 * 25 + oh) * 51 + ow]       = fmaxf(a0[j][jj] + bia0, 0.f);
                c1b[((oc0 + 1) * 25 + oh) * 51 + ow] = fmaxf(a1[j][jj] + bia1, 0.f);
            }
        }
    }
    __syncthreads();   // drains vmem; conv1out complete

    // =================== pool1 -> lds2 (conv2 padded layout [32][16][29]) ===================
    for (int i = tid; i < 32 * 16 * 29; i += 1024) lds2[i] = 0.f;
    __syncthreads();
    for (int u = tid; u < 9600; u += 1024) {       // 32 oc x 12 ph x 25 pw
        int oc = u / 300, rem = u % 300;
        int ph = rem / 25, pw = rem % 25;
        const float* cp = c1b + (oc * 25 + 2 * ph) * 51 + 2 * pw;
        float m = -INFINITY;
        #pragma unroll
        for (int r = 0; r < 3; ++r)
            #pragma unroll
            for (int c = 0; c < 3; ++c)
                m = fmaxf(m, cp[r * 51 + c]);
        lds2[oc * 464 + (ph + 2) * 29 + (pw + 2)] = m;
    }
    __syncthreads();

    // =================== conv2 + pool2 -> p2g (global, L1-hot) ===================
    float* p2b = p2g + b * 64 * 6 * 12;
    for (int u = tid; u < 4608; u += 1024) {       // 64 oc x 6 ph x 12 pw
        int pw = u % 12, ph = (u / 12) % 6, oc = u / 72;
        float acc[2][2] = {{0.f, 0.f}, {0.f, 0.f}};
        const float* wbase = w2 + oc * 32 * 25;
        const float* lbase = lds2 + (2 * ph) * 29 + 2 * pw;
        for (int ic = 0; ic < 32; ++ic) {
            float inr[6][6];
            const float* lp = lbase + ic * 464;
            #pragma unroll
            for (int r = 0; r < 6; ++r)
                #pragma unroll
                for (int c = 0; c < 6; ++c)
                    inr[r][c] = lp[r * 29 + c];
            const float* wp = wbase + ic * 25;
            float wr[25];
            #pragma unroll
            for (int k = 0; k < 25; ++k) wr[k] = wp[k];
            #pragma unroll
            for (int kh = 0; kh < 5; ++kh)
                #pragma unroll
                for (int kw = 0; kw < 5; ++kw)
                    #pragma unroll
                    for (int dy = 0; dy < 2; ++dy)
                        #pragma unroll
                        for (int dx = 0; dx < 2; ++dx)
                            acc[dy][dx] += inr[dy + kh][dx + kw] * wr[kh * 5 + kw];
        }
        float bia = b2[oc];
        p2b[u] = fmaxf(fmaxf(fmaxf(acc[0][0], acc[0][1]),
                             fmaxf(acc[1][0], acc[1][1])) + bia, 0.f);
    }
    __syncthreads();   // p2 complete; lds2 dead

    // =================== stage lds3 [64][8][14] from p2g ===================
    for (int i = tid; i < 64 * 8 * 14; i += 1024) lds3[i] = 0.f;
    __syncthreads();
    for (int i = tid; i < 4608; i += 1024) {
        int oc = i / 72, rem = i % 72;
        int ph = rem / 12, pw = rem % 12;
        lds3[oc * 112 + (ph + 1) * 14 + (pw + 1)] = p2b[i];
    }
    __syncthreads();

    // =================== conv3 + pool3 -> red [128][18] ===================
    for (int u = tid; u < 2304; u += 1024) {       // 128 oc x 3 ph x 6 pw
        int pw = u % 6, ph = (u / 6) % 3, oc = u / 18;
        float acc[2][2] = {{0.f, 0.f}, {0.f, 0.f}};
        const float* wbase = w3 + oc * 64 * 9;
        const float* lbase = lds3 + (2 * ph) * 14 + 2 * pw;
        for (int ic = 0; ic < 64; ++ic) {
            float inr[4][4];
            const float* lp = lbase + ic * 112;
            #pragma unroll
            for (int r = 0; r < 4; ++r)
                #pragma unroll
                for (int c = 0; c < 4; ++c)
                    inr[r][c] = lp[r * 14 + c];
            const float* wp = wbase + ic * 9;
            float wr[9];
            #pragma unroll
            for (int k = 0; k < 9; ++k) wr[k] = wp[k];
            #pragma unroll
            for (int kh = 0; kh < 3; ++kh)
                #pragma unroll
                for (int kw = 0; kw < 3; ++kw)
                    #pragma unroll
                    for (int dy = 0; dy < 2; ++dy)
                        #pragma unroll
                        for (int dx = 0; dx < 2; ++dx)
                            acc[dy][dx] += inr[dy + kh][dx + kw] * wr[kh * 3 + kw];
        }
        float bia = b3[oc];
        red[oc * 18 + ph * 6 + pw] = fmaxf(fmaxf(fmaxf(acc[0][0], acc[0][1]),
                                                 fmaxf(acc[1][0], acc[1][1])) + bia, 0.f);
    }
    __syncthreads();

    // =================== head: mean -> fc1 relu -> fc2 ===================
    if (tid < 128) {
        float s = 0.0f;
        #pragma unroll
        for (int k = 0; k < 18; ++k) s += red[tid * 18 + k];   // row-major order
        feat[tid] = s * (1.0f / 18.0f);
    }
    __syncthreads();
    if (tid < 128) {
        float a = bl1[tid];
        const float4* wr = (const float4*)(wl1 + tid * 128);
        #pragma unroll 8
        for (int k4 = 0; k4 < 32; ++k4) {
            float4 w = wr[k4];
            a += feat[4 * k4] * w.x + feat[4 * k4 + 1] * w.y
               + feat[4 * k4 + 2] * w.z + feat[4 * k4 + 3] * w.w;
        }
        h2[tid] = fmaxf(a, 0.0f);
    }
    __syncthreads();
    if (tid < 5) {
        float a2 = bl2[tid];
        const float4* wr2 = (const float4*)(wl2 + tid * 128);
        #pragma unroll 8
        for (int k4 = 0; k4 < 32; ++k4) {
            float4 w = wr2[k4];
            a2 += h2[4 * k4] * w.x + h2[4 * k4 + 1] * w.y
                + h2[4 * k4 + 2] * w.z + h2[4 * k4 + 3] * w.w;
        }
        out[b * 5 + tid] = a2;
    }
}

// ---------------- launch ----------------
extern "C" void kernel_launch(void* const* d_in, const int* in_sizes, int n_in,
                              void* d_out, int out_size, void* d_ws, size_t ws_size,
                              hipStream_t stream) {
    const int*   x   = (const int*)d_in[0];
    const float* w1  = (const float*)d_in[1];
    const float* b1  = (const float*)d_in[2];
    const float* w2  = (const float*)d_in[3];
    const float* b2  = (const float*)d_in[4];
    const float* w3  = (const float*)d_in[5];
    const float* b3  = (const float*)d_in[6];
    const float* wl1 = (const float*)d_in[7];
    const float* bl1 = (const float*)d_in[8];
    const float* wl2 = (const float*)d_in[9];
    const float* bl2 = (const float*)d_in[10];
    float* out = (float*)d_out;

    // workspace (fully rewritten each launch before any read):
    //   conv1out @ 0       : 10*32*25*51*4 = 1632000 B
    //   p2g      @ 1632000 : 10*64*6*12*4  = 184320 B
    char* ws = (char*)d_ws;
    float* conv1out = (float*)ws;
    float* p2g      = (float*)(ws + 1632000);

    mega_b_kernel<<<Bb, 1024, 0, stream>>>(x, w1, b1, w2, b2, w3, b3,
                                           wl1, bl1, wl2, bl2,
                                           conv1out, p2g, out);
}

// Round 10
// 595.451 us; speedup vs baseline: 1.8624x; 1.8624x over previous
//
#include <hip/hip_runtime.h>

// ---------------- problem constants ----------------
#define Bb 10
#define Hh 50
#define Ww 101
#define Kk 4096

// conv1: IC=3 OC=32 k7 s2 p3 -> [32,25,51]; pool1 k3 s2 -> [32,12,25]
// conv2: IC=32 OC=64 k5 s1 p2 -> [64,12,25]; pool2 k2 s2 -> [64,6,12]
// conv3: IC=64 OC=128 k3 s1 p1 -> [128,6,12]; pool3 k2 s2 -> [128,3,6]
// head: mean(18) -> fc128 relu -> fc5

// ONE kernel, 10 blocks (one per batch) x 1024 threads, all dataflow in-block.
// R9 lesson: 48 live accumulators/thread at 1024 threads -> scratch spill
// (VGPR capped 64, WRITE_SIZE 115MB). v2 keeps live sets <= ~40 regs:
//  - grid stored as BYTES {0,1,2} for all 3 ics simultaneously (18.3 KB LDS),
//    so conv1 loops tasks OUTER / ic INNER with only acc[4] live.
//  - __launch_bounds__(1024, 4) -> 128-VGPR budget (16 waves/CU, 1 blk/CU).
//
// LDS overlays (static 59392 B):
//   S :  gridB[3*56*109]u8 @0 (18312) | lastKp[52*104]int @18312 (21632) ->39944
//   C1:  gridB @0 | w1s[4704]f @18312 (18816) -> 37128
//   C2:  lds2[32*16*29]f @0 (59392)
//   C3:  lds3[64*8*14]f @0 (28672) | red[2304]f @28672 | feat @37888 | h2 @38400
__global__ __launch_bounds__(1024, 4) void mega_b_kernel(
        const int* __restrict__ x,
        const float* __restrict__ w1, const float* __restrict__ b1,
        const float* __restrict__ w2, const float* __restrict__ b2,
        const float* __restrict__ w3, const float* __restrict__ b3,
        const float* __restrict__ wl1, const float* __restrict__ bl1,
        const float* __restrict__ wl2, const float* __restrict__ bl2,
        float* __restrict__ conv1out,   // [10][32][25][51] scratch
        float* __restrict__ p2g,        // [10][64][6][12] scratch
        float* __restrict__ out) {
    __shared__ __align__(16) char smem[59392];
    unsigned char* gridB = (unsigned char*)smem;       // [3][56][109]
    int*   lastKp = (int*)(smem + 18312);              // [52][104]
    float* w1s    = (float*)(smem + 18312);            // 32*3*49 (overlays lastKp)
    float* lds2   = (float*)smem;                      // [32][16][29]
    float* lds3   = (float*)smem;                      // [64][8][14]
    float* red    = (float*)(smem + 28672);            // [128][18]
    float* feat   = (float*)(smem + 37888);            // 128
    float* h2     = (float*)(smem + 38400);            // 128

    int b = blockIdx.x;
    int tid = threadIdx.x;

    // =================== S: scatter + dilate + decode -> byte grid ===================
    for (int ic = 0; ic < 3; ++ic) {
        for (int i = tid; i < 52 * 104; i += 1024) lastKp[i] = -1;
        __syncthreads();
        const int2* xp = (const int2*)(x + (b * 3 + ic) * Kk * 2);   // (col,row)
        for (int k = tid; k < Kk + 1; k += 1024) {
            int col, row;
            if (k == 0) { col = 50; row = 48; }        // prepended base fill
            else { int2 p = xp[k - 1]; col = p.x; row = p.y; }
            atomicMax(&lastKp[(row + 1) * 104 + (col + 1)], k);
        }
        __syncthreads();
        // decode + 3x3 max-dilate into zero-padded byte tile [56][109] (pad=3)
        unsigned char* gB = gridB + ic * 6104;
        for (int i = tid; i < 56 * 109; i += 1024) {
            int r = i / 109, c = i % 109;
            int gr = r - 3, gc = c - 3;
            unsigned char v = 0;
            if (gr >= 0 && gr < Hh && gc >= 0 && gc < Ww) {
                const int* ctr = &lastKp[(gr + 1) * 104 + (gc + 1)];
                int M = ctr[0];
                M = max(M, ctr[-1]);   M = max(M, ctr[1]);
                M = max(M, ctr[-104]); M = max(M, ctr[-105]); M = max(M, ctr[-103]);
                M = max(M, ctr[104]);  M = max(M, ctr[103]);  M = max(M, ctr[105]);
                v = (M < 0) ? 0 : ((ctr[0] == M) ? 2 : 1);   // value = 0.5*v
            }
            gB[i] = v;
        }
        __syncthreads();   // lastKp reused next ic
    }
    // stage w1 into LDS (overlays lastKp, which is now dead)
    for (int i = tid; i < 32 * 3 * 49; i += 1024) w1s[i] = w1[i];
    __syncthreads();

    // =================== C1: conv1 (tasks outer, ic inner; acc[4] live) ===================
    // task = oc*325 + oh*13 + owt  (32*25*13 = 10400), 4 output cols per task
    float* c1b = conv1out + b * 32 * 25 * 51;
    for (int t = tid; t < 10400; t += 1024) {
        int oc = t / 325, rem = t % 325;
        int oh = rem / 13, ow0 = (rem % 13) * 4;
        float acc[4] = {0.f, 0.f, 0.f, 0.f};
        for (int ic = 0; ic < 3; ++ic) {
            const unsigned char* gB = gridB + ic * 6104 + (2 * oh) * 109 + 2 * ow0;
            const float* wp = w1s + (oc * 3 + ic) * 49;
            #pragma unroll
            for (int kh = 0; kh < 7; ++kh) {
                const unsigned char* lr = gB + kh * 109;
                float s[13];
                #pragma unroll
                for (int k = 0; k < 13; ++k) s[k] = 0.5f * (float)lr[k];
                float wa[7];
                #pragma unroll
                for (int k = 0; k < 7; ++k) wa[k] = wp[kh * 7 + k];
                #pragma unroll
                for (int kw = 0; kw < 7; ++kw)
                    #pragma unroll
                    for (int j = 0; j < 4; ++j)
                        acc[j] += s[2 * j + kw] * wa[kw];
            }
        }
        float bia = b1[oc];
        #pragma unroll
        for (int j = 0; j < 4; ++j) {
            int ow = ow0 + j;
            if (ow < 51)
                c1b[(oc * 25 + oh) * 51 + ow] = fmaxf(acc[j] + bia, 0.f);
        }
    }
    __syncthreads();   // conv1out complete (vmem drained by barrier)

    // =================== pool1 -> lds2 (conv2 padded layout [32][16][29]) ===================
    for (int i = tid; i < 32 * 16 * 29; i += 1024) lds2[i] = 0.f;
    __syncthreads();
    for (int u = tid; u < 9600; u += 1024) {       // 32 oc x 12 ph x 25 pw
        int oc = u / 300, rem = u % 300;
        int ph = rem / 25, pw = rem % 25;
        const float* cp = c1b + (oc * 25 + 2 * ph) * 51 + 2 * pw;
        float m = -INFINITY;
        #pragma unroll
        for (int r = 0; r < 3; ++r)
            #pragma unroll
            for (int c = 0; c < 3; ++c)
                m = fmaxf(m, cp[r * 51 + c]);
        lds2[oc * 464 + (ph + 2) * 29 + (pw + 2)] = m;
    }
    __syncthreads();

    // =================== C2: conv2 + pool2 -> p2g (global, L1-hot) ===================
    float* p2b = p2g + b * 64 * 6 * 12;
    for (int u = tid; u < 4608; u += 1024) {       // 64 oc x 6 ph x 12 pw
        int pw = u % 12, ph = (u / 12) % 6, oc = u / 72;
        float acc[2][2] = {{0.f, 0.f}, {0.f, 0.f}};
        const float* wbase = w2 + oc * 32 * 25;
        const float* lbase = lds2 + (2 * ph) * 29 + 2 * pw;
        for (int ic = 0; ic < 32; ++ic) {
            const float* lp = lbase + ic * 464;
            const float* wp = wbase + ic * 25;
            #pragma unroll
            for (int kh = 0; kh < 5; ++kh) {
                float inr[2][6];   // only the 2 pooled rows for this kh
                #pragma unroll
                for (int dy = 0; dy < 2; ++dy)
                    #pragma unroll
                    for (int c = 0; c < 6; ++c)
                        inr[dy][c] = lp[(dy + kh) * 29 + c];
                float wr[5];
                #pragma unroll
                for (int k = 0; k < 5; ++k) wr[k] = wp[kh * 5 + k];
                #pragma unroll
                for (int kw = 0; kw < 5; ++kw)
                    #pragma unroll
                    for (int dy = 0; dy < 2; ++dy)
                        #pragma unroll
                        for (int dx = 0; dx < 2; ++dx)
                            acc[dy][dx] += inr[dy][dx + kw] * wr[kw];
            }
        }
        float bia = b2[oc];
        p2b[u] = fmaxf(fmaxf(fmaxf(acc[0][0], acc[0][1]),
                             fmaxf(acc[1][0], acc[1][1])) + bia, 0.f);
    }
    __syncthreads();   // p2 complete; lds2 dead

    // =================== stage lds3 [64][8][14] from p2g ===================
    for (int i = tid; i < 64 * 8 * 14; i += 1024) lds3[i] = 0.f;
    __syncthreads();
    for (int i = tid; i < 4608; i += 1024) {
        int oc = i / 72, rem = i % 72;
        int ph = rem / 12, pw = rem % 12;
        lds3[oc * 112 + (ph + 1) * 14 + (pw + 1)] = p2b[i];
    }
    __syncthreads();

    // =================== C3: conv3 + pool3 -> red [128][18] ===================
    for (int u = tid; u < 2304; u += 1024) {       // 128 oc x 3 ph x 6 pw
        int pw = u % 6, ph = (u / 6) % 3, oc = u / 18;
        float acc[2][2] = {{0.f, 0.f}, {0.f, 0.f}};
        const float* wbase = w3 + oc * 64 * 9;
        const float* lbase = lds3 + (2 * ph) * 14 + 2 * pw;
        for (int ic = 0; ic < 64; ++ic) {
            float inr[4][4];
            const float* lp = lbase + ic * 112;
            #pragma unroll
            for (int r = 0; r < 4; ++r)
                #pragma unroll
                for (int c = 0; c < 4; ++c)
                    inr[r][c] = lp[r * 14 + c];
            const float* wp = wbase + ic * 9;
            float wr[9];
            #pragma unroll
            for (int k = 0; k < 9; ++k) wr[k] = wp[k];
            #pragma unroll
            for (int kh = 0; kh < 3; ++kh)
                #pragma unroll
                for (int kw = 0; kw < 3; ++kw)
                    #pragma unroll
                    for (int dy = 0; dy < 2; ++dy)
                        #pragma unroll
                        for (int dx = 0; dx < 2; ++dx)
                            acc[dy][dx] += inr[dy + kh][dx + kw] * wr[kh * 3 + kw];
        }
        float bia = b3[oc];
        red[oc * 18 + ph * 6 + pw] = fmaxf(fmaxf(fmaxf(acc[0][0], acc[0][1]),
                                                 fmaxf(acc[1][0], acc[1][1])) + bia, 0.f);
    }
    __syncthreads();

    // =================== head: mean -> fc1 relu -> fc2 ===================
    if (tid < 128) {
        float s = 0.0f;
        #pragma unroll
        for (int k = 0; k < 18; ++k) s += red[tid * 18 + k];   // row-major order
        feat[tid] = s * (1.0f / 18.0f);
    }
    __syncthreads();
    if (tid < 128) {
        float a = bl1[tid];
        const float4* wr = (const float4*)(wl1 + tid * 128);
        #pragma unroll 8
        for (int k4 = 0; k4 < 32; ++k4) {
            float4 w = wr[k4];
            a += feat[4 * k4] * w.x + feat[4 * k4 + 1] * w.y
               + feat[4 * k4 + 2] * w.z + feat[4 * k4 + 3] * w.w;
        }
        h2[tid] = fmaxf(a, 0.0f);
    }
    __syncthreads();
    if (tid < 5) {
        float a2 = bl2[tid];
        const float4* wr2 = (const float4*)(wl2 + tid * 128);
        #pragma unroll 8
        for (int k4 = 0; k4 < 32; ++k4) {
            float4 w = wr2[k4];
            a2 += h2[4 * k4] * w.x + h2[4 * k4 + 1] * w.y
                + h2[4 * k4 + 2] * w.z + h2[4 * k4 + 3] * w.w;
        }
        out[b * 5 + tid] = a2;
    }
}

// ---------------- launch ----------------
extern "C" void kernel_launch(void* const* d_in, const int* in_sizes, int n_in,
                              void* d_out, int out_size, void* d_ws, size_t ws_size,
                              hipStream_t stream) {
    const int*   x   = (const int*)d_in[0];
    const float* w1  = (const float*)d_in[1];
    const float* b1  = (const float*)d_in[2];
    const float* w2  = (const float*)d_in[3];
    const float* b2  = (const float*)d_in[4];
    const float* w3  = (const float*)d_in[5];
    const float* b3  = (const float*)d_in[6];
    const float* wl1 = (const float*)d_in[7];
    const float* bl1 = (const float*)d_in[8];
    const float* wl2 = (const float*)d_in[9];
    const float* bl2 = (const float*)d_in[10];
    float* out = (float*)d_out;

    // workspace (fully rewritten each launch before any read):
    //   conv1out @ 0       : 10*32*25*51*4 = 1632000 B
    //   p2g      @ 1632000 : 10*64*6*12*4  = 184320 B
    char* ws = (char*)d_ws;
    float* conv1out = (float*)ws;
    float* p2g      = (float*)(ws + 1632000);

    mega_b_kernel<<<Bb, 1024, 0, stream>>>(x, w1, b1, w2, b2, w3, b3,
                                           wl1, bl1, wl2, bl2,
                                           conv1out, p2g, out);
}

// Round 11
// 211.894 us; speedup vs baseline: 5.2335x; 2.8101x over previous
//
#include <hip/hip_runtime.h>

// ---------------- problem constants ----------------
#define Bb 10
#define Hh 50
#define Ww 101
#define Kk 4096
#define SLICE (Hh*Ww)   // 5050

// conv1: IC=3 OC=32 k7 s2 p3 -> [32,25,51]; pool1 k3 s2 -> [32,12,25]
// conv2: IC=32 OC=64 k5 s1 p2 -> [64,12,25]; pool2 k2 s2 -> [64,6,12]
// conv3: IC=64 OC=128 k3 s1 p1 -> [128,6,12]; pool3 k2 s2 -> [128,3,6]
// head: mean(18) -> fc128 relu -> fc5

// ============ K0: scatter + separable 3x3 max-dilate + decode -> grid ============
// 30 blocks (one per (b,c) slice) x 1024 threads. Also zeroes cnt[0..9] for K2
// (safe: stream order puts K0 before K2).
__global__ __launch_bounds__(1024) void scatter_grid_kernel(
        const int* __restrict__ x, float* __restrict__ grid, unsigned* __restrict__ cnt) {
    __shared__ int lastKp[52 * 104];   // [row+1][col+1], border -1
    __shared__ int rowm[52 * 104];     // horizontal 3-max
    int bc = blockIdx.x;
    int tid = threadIdx.x;
    if (bc < Bb && tid == 0)
        __hip_atomic_store(&cnt[bc], 0u, __ATOMIC_RELEASE, __HIP_MEMORY_SCOPE_AGENT);
    for (int i = tid; i < 52 * 104; i += 1024) lastKp[i] = -1;
    __syncthreads();
    const int2* xp = (const int2*)(x + bc * Kk * 2);   // (col,row) pairs
    for (int k = tid; k < Kk + 1; k += 1024) {
        int col, row;
        if (k == 0) { col = 50; row = 48; }            // prepended base fill
        else { int2 p = xp[k - 1]; col = p.x; row = p.y; }
        atomicMax(&lastKp[(row + 1) * 104 + (col + 1)], k);
    }
    __syncthreads();
    for (int i = tid; i < 52 * 101; i += 1024) {       // row-max pass
        int r = i / 101, c = i % 101 + 1;
        const int* lp = &lastKp[r * 104 + c];
        rowm[r * 104 + c] = max(max(lp[-1], lp[0]), lp[1]);
    }
    __syncthreads();
    float* g = grid + bc * SLICE;                      // col-max + decode
    for (int i = tid; i < SLICE; i += 1024) {
        int r = i / Ww + 1, c = i % Ww + 1;
        int M = max(max(rowm[(r - 1) * 104 + c], rowm[r * 104 + c]),
                    rowm[(r + 1) * 104 + c]);
        g[i] = (M < 0) ? 0.0f : ((lastKp[r * 104 + c] == M) ? 1.0f : 0.5f);
    }
}

// ================= K1: conv1 + pool1 (R8 verbatim, known-good) =================
__global__ __launch_bounds__(384) void conv1p1_kernel(
        const float* __restrict__ grid, const float* __restrict__ w1,
        const float* __restrict__ b1, float* __restrict__ p1) {
    __shared__ float lds[56 * 109];
    __shared__ float ctile[2 * 25 * 52];   // stride 52 (pad)
    int blk = blockIdx.x;
    int b = blk / 16, ocpair = blk % 16;
    int oc0 = ocpair * 2;
    int tid = threadIdx.x;
    bool active = tid < 325;               // (oh 25) x (owt 13)
    int oh = tid / 13, owt = tid % 13;
    int ow0 = owt * 4;
    float acc0[4] = {0.f, 0.f, 0.f, 0.f};
    float acc1[4] = {0.f, 0.f, 0.f, 0.f};

    for (int ic = 0; ic < 3; ++ic) {
        for (int i = tid; i < 56 * 109; i += 384) {
            int r = i / 109, c = i % 109;
            int gr = r - 3, gc = c - 3;
            float v = 0.f;
            if (gr >= 0 && gr < Hh && gc >= 0 && gc < Ww)
                v = grid[((b * 3 + ic) * Hh + gr) * Ww + gc];
            lds[i] = v;
        }
        __syncthreads();
        if (active) {
            const float* wp0 = w1 + (oc0 * 3 + ic) * 49;
            const float* wp1 = w1 + ((oc0 + 1) * 3 + ic) * 49;
            #pragma unroll
            for (int kh = 0; kh < 7; ++kh) {
                const float* lr = lds + (2 * oh + kh) * 109 + 2 * ow0;
                float s[13];
                #pragma unroll
                for (int k = 0; k < 13; ++k) s[k] = lr[k];
                float wa[7], wb_[7];
                #pragma unroll
                for (int k = 0; k < 7; ++k) { wa[k] = wp0[kh * 7 + k]; wb_[k] = wp1[kh * 7 + k]; }
                #pragma unroll
                for (int kw = 0; kw < 7; ++kw)
                    #pragma unroll
                    for (int j = 0; j < 4; ++j) {
                        acc0[j] += s[2 * j + kw] * wa[kw];
                        acc1[j] += s[2 * j + kw] * wb_[kw];
                    }
            }
        }
        __syncthreads();
    }
    if (active) {
        float bia0 = b1[oc0], bia1 = b1[oc0 + 1];
        #pragma unroll
        for (int j = 0; j < 4; ++j) {
            int ow = ow0 + j;
            if (ow < 51) {
                ctile[(0 * 25 + oh) * 52 + ow] = fmaxf(acc0[j] + bia0, 0.f);
                ctile[(1 * 25 + oh) * 52 + ow] = fmaxf(acc1[j] + bia1, 0.f);
            }
        }
    }
    __syncthreads();
    for (int pu = tid; pu < 600; pu += 384) {    // pool1: 2 oc x 12 x 25
        int oc = pu / 300, rem = pu % 300;
        int ph = rem / 25, pw = rem % 25;
        const float* cp = ctile + (oc * 25 + 2 * ph) * 52 + 2 * pw;
        float m = -INFINITY;
        #pragma unroll
        for (int r = 0; r < 3; ++r)
            #pragma unroll
            for (int c = 0; c < 3; ++c)
                m = fmaxf(m, cp[r * 52 + c]);
        p1[((b * 32 + oc0 + oc) * 12 + ph) * 25 + pw] = m;
    }
}

// ========= K2: conv2+pool2, then last-arriving block does conv3+pool3+head =========
// 90 blocks (9 per b) x 512 threads. Each block computes 512 conv2 outputs and
// publishes them with agent-scope RELEASE atomic stores (R8's proven featbuf
// pattern); 9th-arriving block per b stages p2 via relaxed agent loads and runs
// conv3+pool3+head in-block.
__global__ __launch_bounds__(512) void conv2p3_head_kernel(
        const float* __restrict__ p1, const float* __restrict__ w2,
        const float* __restrict__ b2, const float* __restrict__ w3,
        const float* __restrict__ b3, float* __restrict__ p2g,
        unsigned* __restrict__ cnt,
        const float* __restrict__ wl1, const float* __restrict__ bl1,
        const float* __restrict__ wl2, const float* __restrict__ bl2,
        float* __restrict__ out) {
    __shared__ float lds[32 * 16 * 29];   // 59392 B; overlaid by tail below
    __shared__ unsigned lastflag;
    float* lds3 = lds;                    // [64][8][14] = 7168 f
    float* red  = lds + 7168;             // [128][18]  = 2304 f
    float* feat = lds + 9472;             // 128
    float* h2   = lds + 9600;             // 128  (9728 f = 38912 B < 59392 OK)
    int blk = blockIdx.x;
    int b = blk / 9, blk9 = blk % 9;
    int tid = threadIdx.x;

    // ---- stage p1[b] zero-padded [32][16][29] ----
    for (int i = tid; i < 32 * 16 * 29; i += 512) {
        int ic = i / 464, rem = i % 464;
        int r = rem / 29, c = rem % 29;
        int gr = r - 2, gc = c - 2;
        float v = 0.f;
        if (gr >= 0 && gr < 12 && gc >= 0 && gc < 25)
            v = p1[((b * 32 + ic) * 12 + gr) * 25 + gc];
        lds[i] = v;
    }
    __syncthreads();

    // ---- conv2 + pool2: one output per thread (u = blk9*512 + tid < 4608) ----
    float* p2b = p2g + b * 64 * 6 * 12;
    {
        int u = blk9 * 512 + tid;
        int pw = u % 12, ph = (u / 12) % 6, oc = u / 72;
        float acc[2][2] = {{0.f, 0.f}, {0.f, 0.f}};
        const float* wbase = w2 + oc * 32 * 25;
        const float* lbase = lds + (2 * ph) * 29 + 2 * pw;
        for (int ic = 0; ic < 32; ++ic) {
            float inr[6][6];
            const float* lp = lbase + ic * 464;
            #pragma unroll
            for (int r = 0; r < 6; ++r)
                #pragma unroll
                for (int c = 0; c < 6; ++c)
                    inr[r][c] = lp[r * 29 + c];
            const float* wp = wbase + ic * 25;
            float wr[25];
            #pragma unroll
            for (int k = 0; k < 25; ++k) wr[k] = wp[k];
            #pragma unroll
            for (int kh = 0; kh < 5; ++kh)
                #pragma unroll
                for (int kw = 0; kw < 5; ++kw)
                    #pragma unroll
                    for (int dy = 0; dy < 2; ++dy)
                        #pragma unroll
                        for (int dx = 0; dx < 2; ++dx)
                            acc[dy][dx] += inr[dy + kh][dx + kw] * wr[kh * 5 + kw];
        }
        float bia = b2[oc];
        float m = fmaxf(fmaxf(fmaxf(acc[0][0], acc[0][1]),
                              fmaxf(acc[1][0], acc[1][1])) + bia, 0.f);
        __hip_atomic_store(&p2b[u], m, __ATOMIC_RELEASE, __HIP_MEMORY_SCOPE_AGENT);
    }
    // ---- arrival: 9th block of this b continues; others exit ----
    __syncthreads();
    if (tid == 0) {
        unsigned prev = __hip_atomic_fetch_add(&cnt[b], 1u, __ATOMIC_ACQ_REL,
                                               __HIP_MEMORY_SCOPE_AGENT);
        lastflag = (prev == 8u) ? 1u : 0u;
    }
    __syncthreads();
    if (!lastflag) return;

    // ---- tail: stage p2 into padded lds3 [64][8][14] ----
    for (int i = tid; i < 64 * 8 * 14; i += 512) lds3[i] = 0.f;
    __syncthreads();
    for (int i = tid; i < 4608; i += 512) {
        int oc = i / 72, rem = i % 72;
        int ph = rem / 12, pw = rem % 12;
        float v = __hip_atomic_load(&p2b[i], __ATOMIC_RELAXED, __HIP_MEMORY_SCOPE_AGENT);
        lds3[oc * 112 + (ph + 1) * 14 + (pw + 1)] = v;
    }
    __syncthreads();

    // ---- conv3 + pool3 -> red [128][18] ----
    for (int u = tid; u < 2304; u += 512) {
        int pw = u % 6, ph = (u / 6) % 3, oc = u / 18;
        float acc[2][2] = {{0.f, 0.f}, {0.f, 0.f}};
        const float* wbase = w3 + oc * 64 * 9;
        const float* lbase = lds3 + (2 * ph) * 14 + 2 * pw;
        for (int ic = 0; ic < 64; ++ic) {
            float inr[4][4];
            const float* lp = lbase + ic * 112;
            #pragma unroll
            for (int r = 0; r < 4; ++r)
                #pragma unroll
                for (int c = 0; c < 4; ++c)
                    inr[r][c] = lp[r * 14 + c];
            const float* wp = wbase + ic * 9;
            float wr[9];
            #pragma unroll
            for (int k = 0; k < 9; ++k) wr[k] = wp[k];
            #pragma unroll
            for (int kh = 0; kh < 3; ++kh)
                #pragma unroll
                for (int kw = 0; kw < 3; ++kw)
                    #pragma unroll
                    for (int dy = 0; dy < 2; ++dy)
                        #pragma unroll
                        for (int dx = 0; dx < 2; ++dx)
                            acc[dy][dx] += inr[dy + kh][dx + kw] * wr[kh * 3 + kw];
        }
        float bia = b3[oc];
        red[oc * 18 + ph * 6 + pw] = fmaxf(fmaxf(fmaxf(acc[0][0], acc[0][1]),
                                                 fmaxf(acc[1][0], acc[1][1])) + bia, 0.f);
    }
    __syncthreads();

    // ---- head: mean -> fc1 relu -> fc2 ----
    if (tid < 128) {
        float s = 0.0f;
        #pragma unroll
        for (int k = 0; k < 18; ++k) s += red[tid * 18 + k];   // row-major order
        feat[tid] = s * (1.0f / 18.0f);
    }
    __syncthreads();
    if (tid < 128) {
        float a = bl1[tid];
        const float4* wr = (const float4*)(wl1 + tid * 128);
        #pragma unroll 8
        for (int k4 = 0; k4 < 32; ++k4) {
            float4 w = wr[k4];
            a += feat[4 * k4] * w.x + feat[4 * k4 + 1] * w.y
               + feat[4 * k4 + 2] * w.z + feat[4 * k4 + 3] * w.w;
        }
        h2[tid] = fmaxf(a, 0.0f);
    }
    __syncthreads();
    if (tid < 5) {
        float a2 = bl2[tid];
        const float4* wr2 = (const float4*)(wl2 + tid * 128);
        #pragma unroll 8
        for (int k4 = 0; k4 < 32; ++k4) {
            float4 w = wr2[k4];
            a2 += h2[4 * k4] * w.x + h2[4 * k4 + 1] * w.y
                + h2[4 * k4 + 2] * w.z + h2[4 * k4 + 3] * w.w;
        }
        out[b * 5 + tid] = a2;
    }
}

// ---------------- launch ----------------
extern "C" void kernel_launch(void* const* d_in, const int* in_sizes, int n_in,
                              void* d_out, int out_size, void* d_ws, size_t ws_size,
                              hipStream_t stream) {
    const int*   x   = (const int*)d_in[0];
    const float* w1  = (const float*)d_in[1];
    const float* b1  = (const float*)d_in[2];
    const float* w2  = (const float*)d_in[3];
    const float* b2  = (const float*)d_in[4];
    const float* w3  = (const float*)d_in[5];
    const float* b3  = (const float*)d_in[6];
    const float* wl1 = (const float*)d_in[7];
    const float* bl1 = (const float*)d_in[8];
    const float* wl2 = (const float*)d_in[9];
    const float* bl2 = (const float*)d_in[10];
    float* out = (float*)d_out;

    // workspace:
    //   grid @ 0       : 606000 B
    //   p1   @ 606000  : 384000 B
    //   p2g  @ 990000  : 184320 B
    //   cnt  @ 1174320 : 40 B   (zeroed by K0 each launch, coherent stores)
    char* ws = (char*)d_ws;
    float*    grid = (float*)ws;
    float*    p1   = (float*)(ws + 606000);
    float*    p2g  = (float*)(ws + 990000);
    unsigned* cnt  = (unsigned*)(ws + 1174320);

    scatter_grid_kernel<<<30, 1024, 0, stream>>>(x, grid, cnt);
    conv1p1_kernel<<<160, 384, 0, stream>>>(grid, w1, b1, p1);
    conv2p3_head_kernel<<<90, 512, 0, stream>>>(p1, w2, b2, w3, b3, p2g, cnt,
                                                wl1, bl1, wl2, bl2, out);
}

// Round 12
// 90.582 us; speedup vs baseline: 12.2426x; 2.3393x over previous
//
#include <hip/hip_runtime.h>

// ---------------- problem constants ----------------
#define Bb 10
#define Hh 50
#define Ww 101
#define Kk 4096
#define SLICE (Hh*Ww)   // 5050

// conv1: IC=3 OC=32 k7 s2 p3 -> [32,25,51]; pool1 k3 s2 -> [32,12,25]
// conv2: IC=32 OC=64 k5 s1 p2 -> [64,12,25]; pool2 k2 s2 -> [64,6,12]
// conv3: IC=64 OC=128 k3 s1 p1 -> [128,6,12]; pool3 k2 s2 -> [128,3,6]
// head: mean(18) -> fc128 relu -> fc5

// ============ K0: scatter + separable 3x3 max-dilate + decode -> grid ============
// 30 blocks x 1024 threads (R8 verbatim). Also zeroes cnt[0..9] for K3.
__global__ __launch_bounds__(1024) void scatter_grid_kernel(
        const int* __restrict__ x, float* __restrict__ grid, unsigned* __restrict__ cnt) {
    __shared__ int lastKp[52 * 104];   // [row+1][col+1], border -1
    __shared__ int rowm[52 * 104];     // horizontal 3-max
    int bc = blockIdx.x;
    int tid = threadIdx.x;
    if (bc < Bb && tid == 0)
        __hip_atomic_store(&cnt[bc], 0u, __ATOMIC_RELEASE, __HIP_MEMORY_SCOPE_AGENT);
    for (int i = tid; i < 52 * 104; i += 1024) lastKp[i] = -1;
    __syncthreads();
    const int2* xp = (const int2*)(x + bc * Kk * 2);   // (col,row) pairs
    for (int k = tid; k < Kk + 1; k += 1024) {
        int col, row;
        if (k == 0) { col = 50; row = 48; }            // prepended base fill
        else { int2 p = xp[k - 1]; col = p.x; row = p.y; }
        atomicMax(&lastKp[(row + 1) * 104 + (col + 1)], k);
    }
    __syncthreads();
    for (int i = tid; i < 52 * 101; i += 1024) {       // row-max pass
        int r = i / 101, c = i % 101 + 1;
        const int* lp = &lastKp[r * 104 + c];
        rowm[r * 104 + c] = max(max(lp[-1], lp[0]), lp[1]);
    }
    __syncthreads();
    float* g = grid + bc * SLICE;                      // col-max + decode
    for (int i = tid; i < SLICE; i += 1024) {
        int r = i / Ww + 1, c = i % Ww + 1;
        int M = max(max(rowm[(r - 1) * 104 + c], rowm[r * 104 + c]),
                    rowm[(r + 1) * 104 + c]);
        g[i] = (M < 0) ? 0.0f : ((lastKp[r * 104 + c] == M) ? 1.0f : 0.5f);
    }
}

// ================= K1: conv1 + pool1 (R8 verbatim, known-good) =================
__global__ __launch_bounds__(384) void conv1p1_kernel(
        const float* __restrict__ grid, const float* __restrict__ w1,
        const float* __restrict__ b1, float* __restrict__ p1) {
    __shared__ float lds[56 * 109];
    __shared__ float ctile[2 * 25 * 52];   // stride 52 (pad)
    int blk = blockIdx.x;
    int b = blk / 16, ocpair = blk % 16;
    int oc0 = ocpair * 2;
    int tid = threadIdx.x;
    bool active = tid < 325;               // (oh 25) x (owt 13)
    int oh = tid / 13, owt = tid % 13;
    int ow0 = owt * 4;
    float acc0[4] = {0.f, 0.f, 0.f, 0.f};
    float acc1[4] = {0.f, 0.f, 0.f, 0.f};

    for (int ic = 0; ic < 3; ++ic) {
        for (int i = tid; i < 56 * 109; i += 384) {
            int r = i / 109, c = i % 109;
            int gr = r - 3, gc = c - 3;
            float v = 0.f;
            if (gr >= 0 && gr < Hh && gc >= 0 && gc < Ww)
                v = grid[((b * 3 + ic) * Hh + gr) * Ww + gc];
            lds[i] = v;
        }
        __syncthreads();
        if (active) {
            const float* wp0 = w1 + (oc0 * 3 + ic) * 49;
            const float* wp1 = w1 + ((oc0 + 1) * 3 + ic) * 49;
            #pragma unroll
            for (int kh = 0; kh < 7; ++kh) {
                const float* lr = lds + (2 * oh + kh) * 109 + 2 * ow0;
                float s[13];
                #pragma unroll
                for (int k = 0; k < 13; ++k) s[k] = lr[k];
                float wa[7], wb_[7];
                #pragma unroll
                for (int k = 0; k < 7; ++k) { wa[k] = wp0[kh * 7 + k]; wb_[k] = wp1[kh * 7 + k]; }
                #pragma unroll
                for (int kw = 0; kw < 7; ++kw)
                    #pragma unroll
                    for (int j = 0; j < 4; ++j) {
                        acc0[j] += s[2 * j + kw] * wa[kw];
                        acc1[j] += s[2 * j + kw] * wb_[kw];
                    }
            }
        }
        __syncthreads();
    }
    if (active) {
        float bia0 = b1[oc0], bia1 = b1[oc0 + 1];
        #pragma unroll
        for (int j = 0; j < 4; ++j) {
            int ow = ow0 + j;
            if (ow < 51) {
                ctile[(0 * 25 + oh) * 52 + ow] = fmaxf(acc0[j] + bia0, 0.f);
                ctile[(1 * 25 + oh) * 52 + ow] = fmaxf(acc1[j] + bia1, 0.f);
            }
        }
    }
    __syncthreads();
    for (int pu = tid; pu < 600; pu += 384) {    // pool1: 2 oc x 12 x 25
        int oc = pu / 300, rem = pu % 300;
        int ph = rem / 25, pw = rem % 25;
        const float* cp = ctile + (oc * 25 + 2 * ph) * 52 + 2 * pw;
        float m = -INFINITY;
        #pragma unroll
        for (int r = 0; r < 3; ++r)
            #pragma unroll
            for (int c = 0; c < 3; ++c)
                m = fmaxf(m, cp[r * 52 + c]);
        p1[((b * 32 + oc0 + oc) * 12 + ph) * 25 + pw] = m;
    }
}

// ====== K2: conv2 + pool2 (R8 structure; weight regs ping-pong double-buffered) ======
__global__ void conv2p2_kernel(const float* __restrict__ p1, const float* __restrict__ w2,
                               const float* __restrict__ b2, float* __restrict__ p2) {
    __shared__ float lds[32 * 16 * 29];
    int blk = blockIdx.x;
    int b = blk / 18;
    int tid = threadIdx.x;
    int u = (blk % 18) * 256 + tid;
    for (int i = tid; i < 32 * 16 * 29; i += 256) {
        int ic = i / 464, rem = i % 464;
        int r = rem / 29, c = rem % 29;
        int gr = r - 2, gc = c - 2;
        float v = 0.f;
        if (gr >= 0 && gr < 12 && gc >= 0 && gc < 25)
            v = p1[((b * 32 + ic) * 12 + gr) * 25 + gc];
        lds[i] = v;
    }
    __syncthreads();
    int pw = u % 12, ph = (u / 12) % 6, oc = u / 72;
    float acc[2][2] = {{0.f, 0.f}, {0.f, 0.f}};
    const float* wbase = w2 + oc * 32 * 25;
    const float* lbase = lds + (2 * ph) * 29 + 2 * pw;
    float wrA[25], wrB[25];
    #pragma unroll
    for (int k = 0; k < 25; ++k) wrA[k] = wbase[k];          // ic=0
    #define C2_BODY(IC, WCUR, WNXT, PREFETCH)                                   \
    {                                                                           \
        if (PREFETCH) {                                                         \
            const float* wpn = wbase + ((IC) + 1) * 25;                         \
            _Pragma("unroll")                                                   \
            for (int k = 0; k < 25; ++k) WNXT[k] = wpn[k];                      \
        }                                                                       \
        float inr[6][6];                                                        \
        const float* lp = lbase + (IC) * 464;                                   \
        _Pragma("unroll")                                                       \
        for (int r = 0; r < 6; ++r)                                             \
            _Pragma("unroll")                                                   \
            for (int c = 0; c < 6; ++c)                                         \
                inr[r][c] = lp[r * 29 + c];                                     \
        _Pragma("unroll")                                                       \
        for (int kh = 0; kh < 5; ++kh)                                          \
            _Pragma("unroll")                                                   \
            for (int kw = 0; kw < 5; ++kw)                                      \
                _Pragma("unroll")                                               \
                for (int dy = 0; dy < 2; ++dy)                                  \
                    _Pragma("unroll")                                           \
                    for (int dx = 0; dx < 2; ++dx)                              \
                        acc[dy][dx] += inr[dy + kh][dx + kw] * WCUR[kh * 5 + kw]; \
    }
    for (int ic = 0; ic < 32; ic += 2) {
        C2_BODY(ic,     wrA, wrB, true);
        C2_BODY(ic + 1, wrB, wrA, (ic + 2 < 32));
    }
    #undef C2_BODY
    float bia = b2[oc];
    float m = fmaxf(fmaxf(fmaxf(acc[0][0], acc[0][1]), fmaxf(acc[1][0], acc[1][1])) + bia, 0.f);
    p2[((b * 64 + oc) * 6 + ph) * 12 + pw] = m;
}

// ==== K3: conv3 + pool3 + feat publish + last-block head (R8 structure; w3 ping-pong) ====
__global__ __launch_bounds__(256) void conv3p3_head_kernel(
        const float* __restrict__ p2, const float* __restrict__ w3,
        const float* __restrict__ b3, float* __restrict__ featbuf,
        unsigned* __restrict__ cnt,
        const float* __restrict__ wl1, const float* __restrict__ bl1,
        const float* __restrict__ wl2, const float* __restrict__ bl2,
        float* __restrict__ out) {
    __shared__ float smf[64 * 8 * 14];   // staged p2; later reused for feat/h2
    __shared__ float red[144];
    __shared__ unsigned lastflag;
    int blk = blockIdx.x;
    int b = blk / 16, blk16 = blk % 16;
    int tid = threadIdx.x;
    for (int i = tid; i < 64 * 8 * 14; i += 256) {
        int ic = i / 112, rem = i % 112;
        int r = rem / 14, c = rem % 14;
        int gr = r - 1, gc = c - 1;
        float v = 0.f;
        if (gr >= 0 && gr < 6 && gc >= 0 && gc < 12)
            v = p2[((b * 64 + ic) * 6 + gr) * 12 + gc];
        smf[i] = v;
    }
    __syncthreads();
    if (tid < 144) {
        int u = blk16 * 144 + tid;               // < 2304 = 128*18
        int pw = u % 6, ph = (u / 6) % 3, oc = u / 18;
        float acc[2][2] = {{0.f, 0.f}, {0.f, 0.f}};
        const float* wbase = w3 + oc * 64 * 9;
        const float* lbase = smf + (2 * ph) * 14 + 2 * pw;
        float wrA[9], wrB[9];
        #pragma unroll
        for (int k = 0; k < 9; ++k) wrA[k] = wbase[k];       // ic=0
        #define C3_BODY(IC, WCUR, WNXT, PREFETCH)                               \
        {                                                                       \
            if (PREFETCH) {                                                     \
                const float* wpn = wbase + ((IC) + 1) * 9;                      \
                _Pragma("unroll")                                               \
                for (int k = 0; k < 9; ++k) WNXT[k] = wpn[k];                   \
            }                                                                   \
            float inr[4][4];                                                    \
            const float* lp = lbase + (IC) * 112;                               \
            _Pragma("unroll")                                                   \
            for (int r = 0; r < 4; ++r)                                         \
                _Pragma("unroll")                                               \
                for (int c = 0; c < 4; ++c)                                     \
                    inr[r][c] = lp[r * 14 + c];                                 \
            _Pragma("unroll")                                                   \
            for (int kh = 0; kh < 3; ++kh)                                      \
                _Pragma("unroll")                                               \
                for (int kw = 0; kw < 3; ++kw)                                  \
                    _Pragma("unroll")                                           \
                    for (int dy = 0; dy < 2; ++dy)                              \
                        _Pragma("unroll")                                       \
                        for (int dx = 0; dx < 2; ++dx)                          \
                            acc[dy][dx] += inr[dy + kh][dx + kw] * WCUR[kh * 3 + kw]; \
        }
        for (int ic = 0; ic < 64; ic += 2) {
            C3_BODY(ic,     wrA, wrB, true);
            C3_BODY(ic + 1, wrB, wrA, (ic + 2 < 64));
        }
        #undef C3_BODY
        float bia = b3[oc];
        red[tid] = fmaxf(fmaxf(fmaxf(acc[0][0], acc[0][1]),
                               fmaxf(acc[1][0], acc[1][1])) + bia, 0.f);
    }
    __syncthreads();
    if (tid < 8) {   // reduce this block's 8 complete channels -> feat
        float s = 0.0f;
        #pragma unroll
        for (int k = 0; k < 18; ++k) s += red[tid * 18 + k];   // row-major spatial order
        __hip_atomic_store(&featbuf[b * 128 + blk16 * 8 + tid], s * (1.0f / 18.0f),
                           __ATOMIC_RELEASE, __HIP_MEMORY_SCOPE_AGENT);
    }
    // ---- arrival: 16th block of this b runs the head (no spinning) ----
    __syncthreads();
    if (tid == 0) {
        unsigned prev = __hip_atomic_fetch_add(&cnt[b], 1u, __ATOMIC_ACQ_REL,
                                               __HIP_MEMORY_SCOPE_AGENT);
        lastflag = (prev == 15u) ? 1u : 0u;
    }
    __syncthreads();
    if (lastflag) {
        float* feat = smf;        // overlay (p2 stage dead)
        float* h2 = smf + 128;
        int c = tid;
        if (c < 128)
            feat[c] = __hip_atomic_load(&featbuf[b * 128 + c],
                                        __ATOMIC_ACQUIRE, __HIP_MEMORY_SCOPE_AGENT);
        __syncthreads();
        if (c < 128) {
            float a = bl1[c];
            const float4* wr = (const float4*)(wl1 + c * 128);
            #pragma unroll 8
            for (int k4 = 0; k4 < 32; ++k4) {
                float4 w = wr[k4];
                a += feat[4 * k4] * w.x + feat[4 * k4 + 1] * w.y
                   + feat[4 * k4 + 2] * w.z + feat[4 * k4 + 3] * w.w;
            }
            h2[c] = fmaxf(a, 0.0f);
        }
        __syncthreads();
        if (c < 5) {
            float a2 = bl2[c];
            const float4* wr2 = (const float4*)(wl2 + c * 128);
            #pragma unroll 8
            for (int k4 = 0; k4 < 32; ++k4) {
                float4 w = wr2[k4];
                a2 += h2[4 * k4] * w.x + h2[4 * k4 + 1] * w.y
                    + h2[4 * k4 + 2] * w.z + h2[4 * k4 + 3] * w.w;
            }
            out[b * 5 + c] = a2;
        }
    }
}

// ---------------- launch ----------------
extern "C" void kernel_launch(void* const* d_in, const int* in_sizes, int n_in,
                              void* d_out, int out_size, void* d_ws, size_t ws_size,
                              hipStream_t stream) {
    const int*   x   = (const int*)d_in[0];
    const float* w1  = (const float*)d_in[1];
    const float* b1  = (const float*)d_in[2];
    const float* w2  = (const float*)d_in[3];
    const float* b2  = (const float*)d_in[4];
    const float* w3  = (const float*)d_in[5];
    const float* b3  = (const float*)d_in[6];
    const float* wl1 = (const float*)d_in[7];
    const float* bl1 = (const float*)d_in[8];
    const float* wl2 = (const float*)d_in[9];
    const float* bl2 = (const float*)d_in[10];
    float* out = (float*)d_out;

    // workspace:
    //   grid    @ 0       : 606000 B
    //   p1      @ 606000  : 384000 B
    //   p2g     @ 990000  : 184320 B
    //   featbuf @ 1174320 : 5120 B
    //   cnt     @ 1179440 : 40 B   (zeroed by K0 each launch, coherent stores)
    char* ws = (char*)d_ws;
    float*    grid    = (float*)ws;
    float*    p1      = (float*)(ws + 606000);
    float*    p2g     = (float*)(ws + 990000);
    float*    featbuf = (float*)(ws + 1174320);
    unsigned* cnt     = (unsigned*)(ws + 1179440);

    scatter_grid_kernel<<<30, 1024, 0, stream>>>(x, grid, cnt);
    conv1p1_kernel<<<160, 384, 0, stream>>>(grid, w1, b1, p1);
    conv2p2_kernel<<<180, 256, 0, stream>>>(p1, w2, b2, p2g);
    conv3p3_head_kernel<<<160, 256, 0, stream>>>(p2g, w3, b3, featbuf, cnt,
                                                 wl1, bl1, wl2, bl2, out);
}